// Round 10
// baseline (225.925 us; speedup 1.0000x reference)
//
#include <hip/hip_runtime.h>
#include <hip/hip_bf16.h>

#define DIM    768
#define HEADS  12
#define DHEAD  64
#define BATCH  4
#define SEQ    2048
#define NROW   (BATCH * SEQ)   // 8192
#define QKVN   (3 * DIM)       // 2304
#define FACTOR 0.125f          // 64^-0.5
#define QSCALE 0.18033688011112042f  // FACTOR * log2(e), folded into Q

typedef __attribute__((ext_vector_type(8))) short short8;   // 8 bf16 = 4 VGPR
typedef __attribute__((ext_vector_type(4))) float floatx4;  // 16x16 C/D

__device__ __forceinline__ floatx4 mfma16(short8 a, short8 b, floatx4 c) {
    return __builtin_amdgcn_mfma_f32_16x16x32_bf16(a, b, c, 0, 0, 0);
}

// async global->LDS, 16B per lane; lds base must be wave-uniform,
// deposits at base + lane*16 (lane-ordered source REQUIRED for coalescing)
__device__ __forceinline__ void glds16(const void* g, void* l) {
    __builtin_amdgcn_global_load_lds((const __attribute__((address_space(1))) void*)g,
                                     (__attribute__((address_space(3))) void*)l,
                                     16, 0, 0);
}

// branchless RNE fp32->bf16 (finite values only)
__device__ __forceinline__ short rne16(float f) {
    unsigned u = __builtin_bit_cast(unsigned, f);
    return (short)((u + 0x7fffu + ((u >> 16) & 1u)) >> 16);
}
__device__ __forceinline__ unsigned pack2(float lo, float hi) {
    unsigned ul = __builtin_bit_cast(unsigned, lo);
    unsigned uh = __builtin_bit_cast(unsigned, hi);
    ul = (ul + 0x7fffu + ((ul >> 16) & 1u)) >> 16;
    uh = (uh + 0x7fffu + ((uh >> 16) & 1u)) & 0xffff0000u;
    return ul | uh;
}

// XOR-swizzled tile addressing: 64 bf16 per row, swizzle 16B chunks.
__device__ __forceinline__ int swz8(int row, int col) {
    return (row << 6) + ((((col >> 3) ^ row) & 7) << 3) + (col & 7);
}

// ---------------------------------------------------------------------------
// x fp32 -> bf16
// ---------------------------------------------------------------------------
__global__ __launch_bounds__(256) void conv_bf16(const float* __restrict__ x,
                                                 short* __restrict__ xb) {
    int g = blockIdx.x * 256 + threadIdx.x;
    float4 v = ((const float4*)x)[g];
    uint2 o;
    o.x = pack2(v.x, v.y);
    o.y = pack2(v.z, v.w);
    ((uint2*)xb)[g] = o;
}

// ---------------------------------------------------------------------------
// W [K][N] fp32 -> Wt [N'][K] bf16.  permute=1 (W_qkv): col n = d*36+wh*12+h
// -> row n' = wh*768 + h*64 + d  (GEMM epilogue becomes (wh,h,d)-coalesced).
// ---------------------------------------------------------------------------
__global__ __launch_bounds__(256) void transpose_w(const float* __restrict__ W,
                                                   short* __restrict__ Wt,
                                                   int K, int N, int permute) {
    __shared__ short T[32][33];
    int n0 = blockIdx.x * 32, k0 = blockIdx.y * 32;
    int c = threadIdx.x & 31, r0 = threadIdx.x >> 5;
    for (int r = r0; r < 32; r += 8)
        T[r][c] = rne16(W[(size_t)(k0 + r) * N + n0 + c]);
    __syncthreads();
    for (int r = r0; r < 32; r += 8) {
        int n = n0 + r;
        int np;
        if (permute) {
            int d = n / 36, rem = n - d * 36;
            int which = rem / 12, h = rem - which * 12;
            np = which * 768 + h * 64 + d;
        } else {
            np = n;
        }
        Wt[(size_t)np * K + k0 + c] = T[c][r];
    }
}

// ---------------------------------------------------------------------------
// qkv = xb @ Wqkv (via permuted Wqt [2304][768]); glds-staged.
// Outputs Q,K,V^T as XOR-swizzled 64x64 tiles: [bh][32 tiles][4096 shorts],
// byte-identical to the LDS image attn wants (so attn can glds lane-ordered).
// Q pre-scaled by QSCALE so attention can use exp2(s) directly.
// ---------------------------------------------------------------------------
__global__ __launch_bounds__(256) void gemm_qkv(const short* __restrict__ A,
                                                const short* __restrict__ Bt,
                                                short* __restrict__ Qo,
                                                short* __restrict__ Ko,
                                                short* __restrict__ Vto) {
    __shared__ short As[128 * 64];
    __shared__ short Bs[128 * 64];
    const int tid = threadIdx.x;
    const int lane = tid & 63, wave = tid >> 6;
    const int l15 = lane & 15, quad = lane >> 4;

    // XCD swizzle: 8 XCDs x 8 m x 18 n = 1152 blocks
    const int flat = blockIdx.x;
    const int xcd = flat & 7;
    const int local = flat >> 3;
    const int mloc = local & 7, nloc = local >> 3;
    const int m0 = (xcd * 8 + mloc) * 128;
    const int n0 = nloc * 128;

    const int wm = (wave >> 1) * 64, wn = (wave & 1) * 64;
    const int r8 = wave * 8 + (lane >> 3);
    const int c8 = lane & 7;
    const int sc = ((c8 ^ (r8 & 7)) << 3);   // swizzled source chunk (elems)

    floatx4 acc[4][4] = {};
    for (int k0 = 0; k0 < DIM; k0 += 64) {
#pragma unroll
        for (int i = 0; i < 4; ++i) {
            int row = i * 32 + r8;
            glds16(&A[(size_t)(m0 + row) * DIM + k0 + sc], &As[(size_t)(i * 32 + wave * 8) * 64]);
            glds16(&Bt[(size_t)(n0 + row) * DIM + k0 + sc], &Bs[(size_t)(i * 32 + wave * 8) * 64]);
        }
        __syncthreads();
#pragma unroll
        for (int ks = 0; ks < 2; ++ks) {
            short8 a[4], b[4];
#pragma unroll
            for (int mt = 0; mt < 4; ++mt)
                a[mt] = *(const short8*)&As[swz8(wm + mt * 16 + l15, ks * 32 + quad * 8)];
#pragma unroll
            for (int nt = 0; nt < 4; ++nt)
                b[nt] = *(const short8*)&Bs[swz8(wn + nt * 16 + l15, ks * 32 + quad * 8)];
#pragma unroll
            for (int mt = 0; mt < 4; ++mt)
#pragma unroll
                for (int nt = 0; nt < 4; ++nt)
                    acc[mt][nt] = mfma16(a[mt], b[nt], acc[mt][nt]);
        }
        __syncthreads();
    }

    // ---- epilogue ----
    const int sn = n0 + wn;                 // 64-aligned
    const int which = sn / 768;
    const int h = (sn - which * 768) >> 6;
    const int bb = (m0 + wm) >> 11;
    const int tbase = (m0 + wm) & 2047;
    const size_t tilebase = ((size_t)(bb * HEADS + h) * 32 + (tbase >> 6)) * 4096;

    if (which != 2) {
        // Q/K: scalar stores into the swizzled tile (same 128B lines as linear)
        short* dst = (which == 0) ? Qo : Ko;
        const float scale = (which == 0) ? QSCALE : 1.0f;
#pragma unroll
        for (int mt = 0; mt < 4; ++mt)
#pragma unroll
            for (int nt = 0; nt < 4; ++nt) {
                int d = nt * 16 + l15;
#pragma unroll
                for (int r = 0; r < 4; ++r) {
                    int tl = mt * 16 + quad * 4 + r;
                    dst[tilebase + swz8(tl, d)] = rne16(acc[mt][nt][r] * scale);
                }
            }
    } else {
        // V: build the swizzled V^T 64x64 tile in LDS (vld IS the tile image)
        short* vld = ((wave < 2) ? As : Bs) + (wave & 1) * 4096;  // 64x64
#pragma unroll
        for (int mt = 0; mt < 4; ++mt)
#pragma unroll
            for (int nt = 0; nt < 4; ++nt) {
                int d = nt * 16 + l15;
                int tl = mt * 16 + quad * 4;
                int chunk = (tl >> 3) ^ (d & 7);
                int addr = (d << 6) + (chunk << 3) + (tl & 7);   // = swz8(d, tl)
                uint2 pk;
                pk.x = pack2(acc[mt][nt][0], acc[mt][nt][1]);
                pk.y = pack2(acc[mt][nt][2], acc[mt][nt][3]);
                *(uint2*)&vld[addr] = pk;
            }
    }
    __syncthreads();
    if (which == 2) {
        // linear dump of the swizzled tile -> perfectly coalesced dwordx4
        short* vld = ((wave < 2) ? As : Bs) + (wave & 1) * 4096;
#pragma unroll
        for (int i = 0; i < 8; ++i) {
            int c = (i * 64 + lane) * 8;
            *(uint4*)&Vto[tilebase + c] = *(const uint4*)&vld[c];
        }
    }
}

// ---------------------------------------------------------------------------
// MFMA flash attention, pair-cooperative tiling, un-normalized exp2.
// 512 threads / 8 waves = 4 pairs; pair p owns 32 q-rows. Wave (p,s):
//   S^T for kv-half s (32 kv) x 32 q  -> kf reads halved (4 b128)
//   P into pair-SHARED tile [q32][kv64]; barrier; then PV over FULL kv
//   with d-half s (32 d)              -> V reads halved, disjoint O outputs
// All LDS reads stay 16-row b128 (conflict-free pattern). LDS/chunk: 128 KB
// vs 176 KB for the r9 structure (the measured LDS-BW wall).
// ---------------------------------------------------------------------------
__global__ __launch_bounds__(512, 6) void attn_mfma(const short* __restrict__ Q,
                                                    const short* __restrict__ K,
                                                    const short* __restrict__ Vt,
                                                    short* __restrict__ O) {
    __shared__ __align__(16) short buf[8192];   // Q stage, then K(0..4095)|V(4096..)
    __shared__ __align__(16) short Ps[8192];    // 4 pair tiles [q32][kv64]
    __shared__ float Lx[256];                   // pair x half x 32 q row-sums

    const int tid = threadIdx.x;
    const int lane = tid & 63, wave = tid >> 6;
    const int l15 = lane & 15, quad = lane >> 4;
    const int pair = wave >> 1, sh = wave & 1;
    const int flat = blockIdx.x;
    const int xcd = flat & 7, li = flat >> 3;      // li 0..95
    const int bh = xcd + (li % 6) * 8;             // bh % 8 == xcd
    const int q0 = (li / 6) * 128;
    const size_t base = (size_t)bh * SEQ * DHEAD;  // shorts; = bh*32 tiles
    short* Ks = buf;
    short* Vs = buf + 4096;
    short* Pp = Ps + pair * 2048;
    const int lane8 = lane * 8;

    // ---- stage Q (2 swizzled tiles, 16 KB) lane-ordered ----
    {
        size_t qtb = base + (size_t)(q0 >> 6) * 4096;
#pragma unroll
        for (int i = 0; i < 2; ++i)
            glds16(&Q[qtb + (size_t)(i * 8 + wave) * 512 + lane8],
                   &buf[(i * 8 + wave) * 512]);
    }
    __syncthreads();
    short8 qf[2][2];
#pragma unroll
    for (int mt = 0; mt < 2; ++mt)
#pragma unroll
        for (int ks = 0; ks < 2; ++ks)
            qf[mt][ks] = *(const short8*)&buf[swz8(pair * 32 + mt * 16 + l15,
                                                   ks * 32 + quad * 8)];
    __syncthreads();   // Q in regs; buf now free for K|V

    floatx4 o[2][2] = {};
    float lsum[2] = {0.f, 0.f};

    for (int j0 = 0; j0 < SEQ; j0 += 64) {
        size_t ktb = base + (size_t)(j0 >> 6) * 4096 + wave * 512 + lane8;
        glds16(&K[ktb], &Ks[wave * 512]);
        glds16(&Vt[ktb], &Vs[wave * 512]);
        __syncthreads();

        // S^T half: [kv32 of half sh][q32 of pair]; lane: q=mt*16+l15,
        // kv = sh*32 + kt*16 + quad*4 + r
        floatx4 sa[2][2] = {};
#pragma unroll
        for (int ks = 0; ks < 2; ++ks) {
            short8 kf0 = *(const short8*)&Ks[swz8(sh * 32 + l15, ks * 32 + quad * 8)];
            short8 kf1 = *(const short8*)&Ks[swz8(sh * 32 + 16 + l15, ks * 32 + quad * 8)];
            sa[0][0] = mfma16(kf0, qf[0][ks], sa[0][0]);
            sa[0][1] = mfma16(kf1, qf[0][ks], sa[0][1]);
            sa[1][0] = mfma16(kf0, qf[1][ks], sa[1][0]);
            sa[1][1] = mfma16(kf1, qf[1][ks], sa[1][1]);
        }

        // p = exp2(s) -> pair-shared P tile (b64 packed writes)
#pragma unroll
        for (int mt = 0; mt < 2; ++mt)
#pragma unroll
            for (int kt = 0; kt < 2; ++kt) {
                float p0 = __builtin_amdgcn_exp2f(sa[mt][kt][0]);
                float p1 = __builtin_amdgcn_exp2f(sa[mt][kt][1]);
                float p2 = __builtin_amdgcn_exp2f(sa[mt][kt][2]);
                float p3 = __builtin_amdgcn_exp2f(sa[mt][kt][3]);
                lsum[mt] += (p0 + p1) + (p2 + p3);
                uint2 pk;
                pk.x = pack2(p0, p1);
                pk.y = pack2(p2, p3);
                *(uint2*)&Pp[swz8(mt * 16 + l15, sh * 32 + kt * 16 + quad * 4)] = pk;
            }
        __syncthreads();   // pair P tiles complete

        // O(d-half sh) += P(full kv) . V^T(d-half sh)
#pragma unroll
        for (int ks = 0; ks < 2; ++ks) {
            short8 a0 = *(const short8*)&Pp[swz8(l15, ks * 32 + quad * 8)];
            short8 a1 = *(const short8*)&Pp[swz8(16 + l15, ks * 32 + quad * 8)];
            short8 b0 = *(const short8*)&Vs[swz8(sh * 32 + l15, ks * 32 + quad * 8)];
            short8 b1 = *(const short8*)&Vs[swz8(sh * 32 + 16 + l15, ks * 32 + quad * 8)];
            o[0][0] = mfma16(a0, b0, o[0][0]);
            o[0][1] = mfma16(a0, b1, o[0][1]);
            o[1][0] = mfma16(a1, b0, o[1][0]);
            o[1][1] = mfma16(a1, b1, o[1][1]);
        }
        __syncthreads();   // protect K/V/P from next iteration's writes
    }

    // ---- epilogue ----
    // quad-reduce lsum (value for q = mt*16+l15, this kv-half), share across
    // pair halves via Lx, then redistribute 1/l to C-layout rows and store.
    float r0 = lsum[0], r1 = lsum[1];
    r0 += __shfl_xor(r0, 16); r0 += __shfl_xor(r0, 32);
    r1 += __shfl_xor(r1, 16); r1 += __shfl_xor(r1, 32);
    if (quad == 0) {
        Lx[pair * 64 + sh * 32 + l15] = r0;
        Lx[pair * 64 + sh * 32 + 16 + l15] = r1;
    }
    __syncthreads();
    float inv0 = 1.f / (r0 + Lx[pair * 64 + (sh ^ 1) * 32 + l15]);
    float inv1 = 1.f / (r1 + Lx[pair * 64 + (sh ^ 1) * 32 + 16 + l15]);

    const int b = bh / HEADS, h = bh - b * HEADS;
#pragma unroll
    for (int r = 0; r < 4; ++r) {
        float iv0 = __shfl(inv0, quad * 4 + r);
        float iv1 = __shfl(inv1, quad * 4 + r);
#pragma unroll
        for (int mt = 0; mt < 2; ++mt) {
            int t = q0 + pair * 32 + mt * 16 + quad * 4 + r;
            float iv = mt ? iv1 : iv0;
            size_t rowo = ((size_t)(b * SEQ + t)) * DIM + h * DHEAD + sh * 32;
            O[rowo + l15] = rne16(o[mt][0][r] * iv);
            O[rowo + 16 + l15] = rne16(o[mt][1][r] * iv);
        }
    }
}

// ---------------------------------------------------------------------------
// out = attnB @ Wout (via Wot [768][768]), fp32 output; glds-staged.
// ---------------------------------------------------------------------------
__global__ __launch_bounds__(256) void gemm_out(const short* __restrict__ A,
                                                const short* __restrict__ Bt,
                                                float* __restrict__ out) {
    __shared__ short As[128 * 64];
    __shared__ short Bs[128 * 64];
    const int tid = threadIdx.x;
    const int lane = tid & 63, wave = tid >> 6;
    const int l15 = lane & 15, quad = lane >> 4;
    const int m0 = blockIdx.y * 128, n0 = blockIdx.x * 128;
    const int wm = (wave >> 1) * 64, wn = (wave & 1) * 64;
    const int r8 = wave * 8 + (lane >> 3);
    const int sc = (((lane & 7) ^ (r8 & 7)) << 3);

    floatx4 acc[4][4] = {};
    for (int k0 = 0; k0 < DIM; k0 += 64) {
#pragma unroll
        for (int i = 0; i < 4; ++i) {
            int row = i * 32 + r8;
            glds16(&A[(size_t)(m0 + row) * DIM + k0 + sc], &As[(size_t)(i * 32 + wave * 8) * 64]);
            glds16(&Bt[(size_t)(n0 + row) * DIM + k0 + sc], &Bs[(size_t)(i * 32 + wave * 8) * 64]);
        }
        __syncthreads();
#pragma unroll
        for (int ks = 0; ks < 2; ++ks) {
            short8 a[4], b[4];
#pragma unroll
            for (int mt = 0; mt < 4; ++mt)
                a[mt] = *(const short8*)&As[swz8(wm + mt * 16 + l15, ks * 32 + quad * 8)];
#pragma unroll
            for (int nt = 0; nt < 4; ++nt)
                b[nt] = *(const short8*)&Bs[swz8(wn + nt * 16 + l15, ks * 32 + quad * 8)];
#pragma unroll
            for (int mt = 0; mt < 4; ++mt)
#pragma unroll
                for (int nt = 0; nt < 4; ++nt)
                    acc[mt][nt] = mfma16(a[mt], b[nt], acc[mt][nt]);
        }
        __syncthreads();
    }

#pragma unroll
    for (int mt = 0; mt < 4; ++mt)
#pragma unroll
        for (int nt = 0; nt < 4; ++nt)
#pragma unroll
            for (int r = 0; r < 4; ++r) {
                int m = m0 + wm + mt * 16 + quad * 4 + r;
                int n = n0 + wn + nt * 16 + l15;
                out[(size_t)m * DIM + n] = acc[mt][nt][r];
            }
}

// ---------------------------------------------------------------------------
extern "C" void kernel_launch(void* const* d_in, const int* in_sizes, int n_in,
                              void* d_out, int out_size, void* d_ws, size_t ws_size,
                              hipStream_t stream) {
    const float* x    = (const float*)d_in[0];  // [4,2048,768] fp32
    const float* Wqkv = (const float*)d_in[1];  // [768,2304]  fp32
    const float* Wout = (const float*)d_in[2];  // [768,768]   fp32
    float* out = (float*)d_out;                 // [4,2048,768] fp32

    const size_t NE = (size_t)NROW * DIM;       // 6291456
    short* xb  = (short*)d_ws;                  // x bf16; later reused as attnB
    short* Wqt = xb + NE;                       // [2304][768] (col-permuted)
    short* Wot = Wqt + (size_t)QKVN * DIM;      // [768][768]
    short* Qw  = Wot + (size_t)DIM * DIM;       // swizzled tiles (pre-scaled)
    short* Kw  = Qw + NE;                       // swizzled tiles
    short* Vtw = Kw + NE;                       // swizzled V^T tiles

    conv_bf16<<<NE / 4 / 256, 256, 0, stream>>>(x, xb);
    transpose_w<<<dim3(QKVN / 32, DIM / 32), 256, 0, stream>>>(Wqkv, Wqt, DIM, QKVN, 1);
    transpose_w<<<dim3(DIM / 32, DIM / 32), 256, 0, stream>>>(Wout, Wot, DIM, DIM, 0);
    gemm_qkv<<<8 * 8 * 18, 256, 0, stream>>>(xb, Wqt, Qw, Kw, Vtw);
    // xb (x in bf16) is dead after gemm_qkv -> reuse as attention output buffer
    attn_mfma<<<768, 512, 0, stream>>>(Qw, Kw, Vtw, xb);
    gemm_out<<<dim3(DIM / 128, NROW / 128), 256, 0, stream>>>(xb, Wot, out);
}

// Round 11
// 218.969 us; speedup vs baseline: 1.0318x; 1.0318x over previous
//
#include <hip/hip_runtime.h>
#include <hip/hip_bf16.h>

#define DIM    768
#define HEADS  12
#define DHEAD  64
#define BATCH  4
#define SEQ    2048
#define NROW   (BATCH * SEQ)   // 8192
#define QKVN   (3 * DIM)       // 2304
#define FACTOR 0.125f          // 64^-0.5
#define QSCALE 0.18033688011112042f  // FACTOR * log2(e), folded into Wqt rows <768

typedef __attribute__((ext_vector_type(8))) short short8;   // 8 bf16 = 4 VGPR
typedef __attribute__((ext_vector_type(4))) float floatx4;  // 16x16 C/D

__device__ __forceinline__ floatx4 mfma16(short8 a, short8 b, floatx4 c) {
    return __builtin_amdgcn_mfma_f32_16x16x32_bf16(a, b, c, 0, 0, 0);
}

// async global->LDS, 16B per lane; lds base must be wave-uniform,
// deposits at base + lane*16 (lane-ordered source REQUIRED for coalescing)
__device__ __forceinline__ void glds16(const void* g, void* l) {
    __builtin_amdgcn_global_load_lds((const __attribute__((address_space(1))) void*)g,
                                     (__attribute__((address_space(3))) void*)l,
                                     16, 0, 0);
}

// branchless RNE fp32->bf16 (finite values only)
__device__ __forceinline__ short rne16(float f) {
    unsigned u = __builtin_bit_cast(unsigned, f);
    return (short)((u + 0x7fffu + ((u >> 16) & 1u)) >> 16);
}
__device__ __forceinline__ unsigned pack2(float lo, float hi) {
    unsigned ul = __builtin_bit_cast(unsigned, lo);
    unsigned uh = __builtin_bit_cast(unsigned, hi);
    ul = (ul + 0x7fffu + ((ul >> 16) & 1u)) >> 16;
    uh = (uh + 0x7fffu + ((uh >> 16) & 1u)) & 0xffff0000u;
    return ul | uh;
}

// XOR-swizzled tile addressing: 64 bf16 per row, swizzle 16B chunks.
__device__ __forceinline__ int swz8(int row, int col) {
    return (row << 6) + ((((col >> 3) ^ row) & 7) << 3) + (col & 7);
}

// ---------------------------------------------------------------------------
// prep (fused): blocks [0,6144)   : x fp32 -> bf16
//               blocks [6144,7872): Wqkv transpose+permute (+QSCALE rows<768)
//               blocks [7872,8448): Wout transpose
// ---------------------------------------------------------------------------
__global__ __launch_bounds__(256) void prep(const float* __restrict__ x,
                                            short* __restrict__ xb,
                                            const float* __restrict__ Wqkv,
                                            short* __restrict__ Wqt,
                                            const float* __restrict__ Wout,
                                            short* __restrict__ Wot) {
    __shared__ short T[32][33];
    int blk = blockIdx.x;
    if (blk < 6144) {
        int g = blk * 256 + threadIdx.x;
        float4 v = ((const float4*)x)[g];
        uint2 o;
        o.x = pack2(v.x, v.y);
        o.y = pack2(v.z, v.w);
        ((uint2*)xb)[g] = o;
        return;
    }
    blk -= 6144;
    const float* W;
    short* Wt;
    int N, permute, bx, by;
    if (blk < 1728) { W = Wqkv; Wt = Wqt; N = QKVN; permute = 1; bx = blk % 72; by = blk / 72; }
    else { blk -= 1728; W = Wout; Wt = Wot; N = DIM; permute = 0; bx = blk % 24; by = blk / 24; }

    int n0 = bx * 32, k0 = by * 32;
    int c = threadIdx.x & 31, r0 = threadIdx.x >> 5;
    for (int r = r0; r < 32; r += 8)
        T[r][c] = rne16(W[(size_t)(k0 + r) * N + n0 + c]);
    __syncthreads();
    for (int r = r0; r < 32; r += 8) {
        int n = n0 + r;
        int np = n;
        float scale = 1.0f;
        if (permute) {
            int d = n / 36, rem = n - d * 36;
            int which = rem / 12, h = rem - which * 12;
            np = which * 768 + h * 64 + d;
            if (which == 0) scale = QSCALE;
        }
        float v = __bfloat162float(__hip_bfloat16_raw{(unsigned short)T[c][r]});
        Wt[(size_t)np * DIM + k0 + c] = (scale == 1.0f) ? T[c][r] : rne16(v * scale);
    }
}

// ---------------------------------------------------------------------------
// qkv = xb @ Wqkv (via permuted Wqt [2304][768]); glds-staged.
// Outputs Q,K,V^T as XOR-swizzled 64x64 tiles [bh][32 tiles][4096 shorts].
// Q/K waves run the MFMA with SWAPPED operands (C^T): lane holds 4
// consecutive d at fixed t -> packed uint2 stores (16/lane, not 64 scalar).
// V waves keep orientation (4 consecutive t at fixed d) -> LDS transpose.
// ---------------------------------------------------------------------------
__global__ __launch_bounds__(256) void gemm_qkv(const short* __restrict__ A,
                                                const short* __restrict__ Bt,
                                                short* __restrict__ Qo,
                                                short* __restrict__ Ko,
                                                short* __restrict__ Vto) {
    __shared__ short As[128 * 64];
    __shared__ short Bs[128 * 64];
    const int tid = threadIdx.x;
    const int lane = tid & 63, wave = tid >> 6;
    const int l15 = lane & 15, quad = lane >> 4;

    // XCD swizzle: 8 XCDs x 8 m x 18 n = 1152 blocks
    const int flat = blockIdx.x;
    const int xcd = flat & 7;
    const int local = flat >> 3;
    const int mloc = local & 7, nloc = local >> 3;
    const int m0 = (xcd * 8 + mloc) * 128;
    const int n0 = nloc * 128;

    const int wm = (wave >> 1) * 64, wn = (wave & 1) * 64;
    const int r8 = wave * 8 + (lane >> 3);
    const int c8 = lane & 7;
    const int sc = ((c8 ^ (r8 & 7)) << 3);   // swizzled source chunk (elems)

    const int sn = n0 + wn;                  // wave-uniform output chunk
    const int which = sn / 768;
    const bool swapAB = (which != 2);        // Q/K waves compute C^T

    floatx4 acc[4][4] = {};
    for (int k0 = 0; k0 < DIM; k0 += 64) {
#pragma unroll
        for (int i = 0; i < 4; ++i) {
            int row = i * 32 + r8;
            glds16(&A[(size_t)(m0 + row) * DIM + k0 + sc], &As[(size_t)(i * 32 + wave * 8) * 64]);
            glds16(&Bt[(size_t)(n0 + row) * DIM + k0 + sc], &Bs[(size_t)(i * 32 + wave * 8) * 64]);
        }
        __syncthreads();
#pragma unroll
        for (int ks = 0; ks < 2; ++ks) {
            short8 a[4], b[4];
#pragma unroll
            for (int mt = 0; mt < 4; ++mt)
                a[mt] = *(const short8*)&As[swz8(wm + mt * 16 + l15, ks * 32 + quad * 8)];
#pragma unroll
            for (int nt = 0; nt < 4; ++nt)
                b[nt] = *(const short8*)&Bs[swz8(wn + nt * 16 + l15, ks * 32 + quad * 8)];
            if (swapAB) {
#pragma unroll
                for (int mt = 0; mt < 4; ++mt)
#pragma unroll
                    for (int nt = 0; nt < 4; ++nt)
                        acc[mt][nt] = mfma16(b[nt], a[mt], acc[mt][nt]);
            } else {
#pragma unroll
                for (int mt = 0; mt < 4; ++mt)
#pragma unroll
                    for (int nt = 0; nt < 4; ++nt)
                        acc[mt][nt] = mfma16(a[mt], b[nt], acc[mt][nt]);
            }
        }
        __syncthreads();
    }

    // ---- epilogue ----
    const int h = (sn - which * 768) >> 6;
    const int bb = (m0 + wm) >> 11;
    const int tbase = (m0 + wm) & 2047;
    const size_t tilebase = ((size_t)(bb * HEADS + h) * 32 + (tbase >> 6)) * 4096;

    if (which != 2) {
        // swapped acc: lane covers t = mt*16+l15, d = nt*16+quad*4..+3
        short* dst = (which == 0) ? Qo : Ko;
#pragma unroll
        for (int mt = 0; mt < 4; ++mt)
#pragma unroll
            for (int nt = 0; nt < 4; ++nt) {
                int tl = mt * 16 + l15;
                int d0 = nt * 16 + quad * 4;
                uint2 pk;
                pk.x = pack2(acc[mt][nt][0], acc[mt][nt][1]);
                pk.y = pack2(acc[mt][nt][2], acc[mt][nt][3]);
                *(uint2*)&dst[tilebase + swz8(tl, d0)] = pk;
            }
    } else {
        // V: build the swizzled V^T 64x64 tile in LDS (vld IS the tile image)
        short* vld = ((wave < 2) ? As : Bs) + (wave & 1) * 4096;  // 64x64
#pragma unroll
        for (int mt = 0; mt < 4; ++mt)
#pragma unroll
            for (int nt = 0; nt < 4; ++nt) {
                int d = nt * 16 + l15;
                int tl = mt * 16 + quad * 4;
                int chunk = (tl >> 3) ^ (d & 7);
                int addr = (d << 6) + (chunk << 3) + (tl & 7);   // = swz8(d, tl)
                uint2 pk;
                pk.x = pack2(acc[mt][nt][0], acc[mt][nt][1]);
                pk.y = pack2(acc[mt][nt][2], acc[mt][nt][3]);
                *(uint2*)&vld[addr] = pk;
            }
    }
    __syncthreads();
    if (which == 2) {
        // linear dump of the swizzled tile -> perfectly coalesced dwordx4
        short* vld = ((wave < 2) ? As : Bs) + (wave & 1) * 4096;
#pragma unroll
        for (int i = 0; i < 8; ++i) {
            int c = (i * 64 + lane) * 8;
            *(uint4*)&Vto[tilebase + c] = *(const uint4*)&vld[c];
        }
    }
}

// ---------------------------------------------------------------------------
// MFMA flash attention, pair-cooperative tiling, un-normalized exp2.
// (unchanged from r10 — 512 thr / 4 pairs; S^T kv-split, PV d-split)
// ---------------------------------------------------------------------------
__global__ __launch_bounds__(512, 6) void attn_mfma(const short* __restrict__ Q,
                                                    const short* __restrict__ K,
                                                    const short* __restrict__ Vt,
                                                    short* __restrict__ O) {
    __shared__ __align__(16) short buf[8192];   // Q stage, then K(0..4095)|V(4096..)
    __shared__ __align__(16) short Ps[8192];    // 4 pair tiles [q32][kv64]
    __shared__ float Lx[256];                   // pair x half x 32 q row-sums

    const int tid = threadIdx.x;
    const int lane = tid & 63, wave = tid >> 6;
    const int l15 = lane & 15, quad = lane >> 4;
    const int pair = wave >> 1, sh = wave & 1;
    const int flat = blockIdx.x;
    const int xcd = flat & 7, li = flat >> 3;      // li 0..95
    const int bh = xcd + (li % 6) * 8;             // bh % 8 == xcd
    const int q0 = (li / 6) * 128;
    const size_t base = (size_t)bh * SEQ * DHEAD;  // shorts; = bh*32 tiles
    short* Ks = buf;
    short* Vs = buf + 4096;
    short* Pp = Ps + pair * 2048;
    const int lane8 = lane * 8;

    // ---- stage Q (2 swizzled tiles, 16 KB) lane-ordered ----
    {
        size_t qtb = base + (size_t)(q0 >> 6) * 4096;
#pragma unroll
        for (int i = 0; i < 2; ++i)
            glds16(&Q[qtb + (size_t)(i * 8 + wave) * 512 + lane8],
                   &buf[(i * 8 + wave) * 512]);
    }
    __syncthreads();
    short8 qf[2][2];
#pragma unroll
    for (int mt = 0; mt < 2; ++mt)
#pragma unroll
        for (int ks = 0; ks < 2; ++ks)
            qf[mt][ks] = *(const short8*)&buf[swz8(pair * 32 + mt * 16 + l15,
                                                   ks * 32 + quad * 8)];
    __syncthreads();   // Q in regs; buf now free for K|V

    floatx4 o[2][2] = {};
    float lsum[2] = {0.f, 0.f};

    for (int j0 = 0; j0 < SEQ; j0 += 64) {
        size_t ktb = base + (size_t)(j0 >> 6) * 4096 + wave * 512 + lane8;
        glds16(&K[ktb], &Ks[wave * 512]);
        glds16(&Vt[ktb], &Vs[wave * 512]);
        __syncthreads();

        // S^T half: [kv32 of half sh][q32 of pair]
        floatx4 sa[2][2] = {};
#pragma unroll
        for (int ks = 0; ks < 2; ++ks) {
            short8 kf0 = *(const short8*)&Ks[swz8(sh * 32 + l15, ks * 32 + quad * 8)];
            short8 kf1 = *(const short8*)&Ks[swz8(sh * 32 + 16 + l15, ks * 32 + quad * 8)];
            sa[0][0] = mfma16(kf0, qf[0][ks], sa[0][0]);
            sa[0][1] = mfma16(kf1, qf[0][ks], sa[0][1]);
            sa[1][0] = mfma16(kf0, qf[1][ks], sa[1][0]);
            sa[1][1] = mfma16(kf1, qf[1][ks], sa[1][1]);
        }

        // p = exp2(s) -> pair-shared P tile (b64 packed writes)
#pragma unroll
        for (int mt = 0; mt < 2; ++mt)
#pragma unroll
            for (int kt = 0; kt < 2; ++kt) {
                float p0 = __builtin_amdgcn_exp2f(sa[mt][kt][0]);
                float p1 = __builtin_amdgcn_exp2f(sa[mt][kt][1]);
                float p2 = __builtin_amdgcn_exp2f(sa[mt][kt][2]);
                float p3 = __builtin_amdgcn_exp2f(sa[mt][kt][3]);
                lsum[mt] += (p0 + p1) + (p2 + p3);
                uint2 pk;
                pk.x = pack2(p0, p1);
                pk.y = pack2(p2, p3);
                *(uint2*)&Pp[swz8(mt * 16 + l15, sh * 32 + kt * 16 + quad * 4)] = pk;
            }
        __syncthreads();   // pair P tiles complete

        // O(d-half sh) += P(full kv) . V^T(d-half sh)
#pragma unroll
        for (int ks = 0; ks < 2; ++ks) {
            short8 a0 = *(const short8*)&Pp[swz8(l15, ks * 32 + quad * 8)];
            short8 a1 = *(const short8*)&Pp[swz8(16 + l15, ks * 32 + quad * 8)];
            short8 b0 = *(const short8*)&Vs[swz8(sh * 32 + l15, ks * 32 + quad * 8)];
            short8 b1 = *(const short8*)&Vs[swz8(sh * 32 + 16 + l15, ks * 32 + quad * 8)];
            o[0][0] = mfma16(a0, b0, o[0][0]);
            o[0][1] = mfma16(a0, b1, o[0][1]);
            o[1][0] = mfma16(a1, b0, o[1][0]);
            o[1][1] = mfma16(a1, b1, o[1][1]);
        }
        __syncthreads();   // protect K/V/P from next iteration's writes
    }

    // ---- epilogue ----
    float r0 = lsum[0], r1 = lsum[1];
    r0 += __shfl_xor(r0, 16); r0 += __shfl_xor(r0, 32);
    r1 += __shfl_xor(r1, 16); r1 += __shfl_xor(r1, 32);
    if (quad == 0) {
        Lx[pair * 64 + sh * 32 + l15] = r0;
        Lx[pair * 64 + sh * 32 + 16 + l15] = r1;
    }
    __syncthreads();
    float inv0 = 1.f / (r0 + Lx[pair * 64 + (sh ^ 1) * 32 + l15]);
    float inv1 = 1.f / (r1 + Lx[pair * 64 + (sh ^ 1) * 32 + 16 + l15]);

    const int b = bh / HEADS, h = bh - b * HEADS;
#pragma unroll
    for (int r = 0; r < 4; ++r) {
        float iv0 = __shfl(inv0, quad * 4 + r);
        float iv1 = __shfl(inv1, quad * 4 + r);
#pragma unroll
        for (int mt = 0; mt < 2; ++mt) {
            int t = q0 + pair * 32 + mt * 16 + quad * 4 + r;
            float iv = mt ? iv1 : iv0;
            size_t rowo = ((size_t)(b * SEQ + t)) * DIM + h * DHEAD + sh * 32;
            O[rowo + l15] = rne16(o[mt][0][r] * iv);
            O[rowo + 16 + l15] = rne16(o[mt][1][r] * iv);
        }
    }
}

// ---------------------------------------------------------------------------
// out = attnB @ Wout (via Wot [768][768]), fp32 output; glds-staged.
// All waves SWAP operands (C^T): lane holds 4 consecutive n at fixed m ->
// one dwordx4 store per acc (16/lane, not 64 scalar dwords).
// ---------------------------------------------------------------------------
__global__ __launch_bounds__(256) void gemm_out(const short* __restrict__ A,
                                                const short* __restrict__ Bt,
                                                float* __restrict__ out) {
    __shared__ short As[128 * 64];
    __shared__ short Bs[128 * 64];
    const int tid = threadIdx.x;
    const int lane = tid & 63, wave = tid >> 6;
    const int l15 = lane & 15, quad = lane >> 4;
    const int m0 = blockIdx.y * 128, n0 = blockIdx.x * 128;
    const int wm = (wave >> 1) * 64, wn = (wave & 1) * 64;
    const int r8 = wave * 8 + (lane >> 3);
    const int sc = (((lane & 7) ^ (r8 & 7)) << 3);

    floatx4 acc[4][4] = {};
    for (int k0 = 0; k0 < DIM; k0 += 64) {
#pragma unroll
        for (int i = 0; i < 4; ++i) {
            int row = i * 32 + r8;
            glds16(&A[(size_t)(m0 + row) * DIM + k0 + sc], &As[(size_t)(i * 32 + wave * 8) * 64]);
            glds16(&Bt[(size_t)(n0 + row) * DIM + k0 + sc], &Bs[(size_t)(i * 32 + wave * 8) * 64]);
        }
        __syncthreads();
#pragma unroll
        for (int ks = 0; ks < 2; ++ks) {
            short8 a[4], b[4];
#pragma unroll
            for (int mt = 0; mt < 4; ++mt)
                a[mt] = *(const short8*)&As[swz8(wm + mt * 16 + l15, ks * 32 + quad * 8)];
#pragma unroll
            for (int nt = 0; nt < 4; ++nt)
                b[nt] = *(const short8*)&Bs[swz8(wn + nt * 16 + l15, ks * 32 + quad * 8)];
#pragma unroll
            for (int mt = 0; mt < 4; ++mt)
#pragma unroll
                for (int nt = 0; nt < 4; ++nt)
                    acc[mt][nt] = mfma16(b[nt], a[mt], acc[mt][nt]);  // C^T
        }
        __syncthreads();
    }

    // swapped: m = wm+mt*16+l15, n = wn+nt*16+quad*4..+3 -> dwordx4 stores
#pragma unroll
    for (int mt = 0; mt < 4; ++mt)
#pragma unroll
        for (int nt = 0; nt < 4; ++nt) {
            int m = m0 + wm + mt * 16 + l15;
            int n = n0 + wn + nt * 16 + quad * 4;
            *(floatx4*)&out[(size_t)m * DIM + n] = acc[mt][nt];
        }
}

// ---------------------------------------------------------------------------
extern "C" void kernel_launch(void* const* d_in, const int* in_sizes, int n_in,
                              void* d_out, int out_size, void* d_ws, size_t ws_size,
                              hipStream_t stream) {
    const float* x    = (const float*)d_in[0];  // [4,2048,768] fp32
    const float* Wqkv = (const float*)d_in[1];  // [768,2304]  fp32
    const float* Wout = (const float*)d_in[2];  // [768,768]   fp32
    float* out = (float*)d_out;                 // [4,2048,768] fp32

    const size_t NE = (size_t)NROW * DIM;       // 6291456
    short* xb  = (short*)d_ws;                  // x bf16; later reused as attnB
    short* Wqt = xb + NE;                       // [2304][768] (col-permuted, Q-rows pre-scaled)
    short* Wot = Wqt + (size_t)QKVN * DIM;      // [768][768]
    short* Qw  = Wot + (size_t)DIM * DIM;       // swizzled tiles
    short* Kw  = Qw + NE;                       // swizzled tiles
    short* Vtw = Kw + NE;                       // swizzled V^T tiles

    prep<<<6144 + 1728 + 576, 256, 0, stream>>>(x, xb, Wqkv, Wqt, Wout, Wot);
    gemm_qkv<<<8 * 8 * 18, 256, 0, stream>>>(xb, Wqt, Qw, Kw, Vtw);
    // xb (x in bf16) is dead after gemm_qkv -> reuse as attention output buffer
    attn_mfma<<<768, 512, 0, stream>>>(Qw, Kw, Vtw, xb);
    gemm_out<<<dim3(DIM / 128, NROW / 128), 256, 0, stream>>>(xb, Wot, out);
}